// Round 1
// baseline (96.144 us; speedup 1.0000x reference)
//
#include <hip/hip_runtime.h>
#include <math.h>

// Problem constants (from reference):
//   x: (16, 3, 448, 448) fp32; PH=PW=14 -> Hp=Wp=32; DCT 3x3; 12x12=144 windows/patch
//   out: (16, 32, 32) fp32 = richness.mean(channel)

__global__ __launch_bounds__(192) void richness_kernel(
    const float* __restrict__ x,
    const float* __restrict__ dctm,
    float* __restrict__ out)
{
    const int bid  = blockIdx.x;          // b*1024 + hp*32 + wp
    const int wp   = bid & 31;
    const int hp   = (bid >> 5) & 31;
    const int b    = bid >> 10;
    const int wave = threadIdx.x >> 6;    // channel 0..2
    const int lane = threadIdx.x & 63;

    __shared__ float patch[3][14][16];    // +2 pad per row
    __shared__ int   hist[3][256];
    __shared__ float partial[3];

    // DCT matrix -> registers (uniform broadcast loads)
    float D[3][3];
#pragma unroll
    for (int i = 0; i < 3; ++i)
#pragma unroll
        for (int j = 0; j < 3; ++j)
            D[i][j] = dctm[i * 3 + j];

    // zero histogram
    for (int i = lane; i < 256; i += 64) hist[wave][i] = 0;
    __syncthreads();

    // stage patch in LDS + histogram
    const float* src = x + (((size_t)(b * 3 + wave) * 448 + hp * 14) * 448) + wp * 14;
    for (int idx = lane; idx < 196; idx += 64) {
        int r = idx / 14;
        int q = idx - r * 14;
        float v = src[r * 448 + q];
        patch[wave][r][q] = v;
        int bin = (int)rintf(v * 255.0f);   // round-half-even, matches np.round
        bin = bin < 0 ? 0 : (bin > 255 ? 255 : bin);
        atomicAdd(&hist[wave][bin], 1);
    }
    __syncthreads();

    // ---- entropy: 4 bins per lane ----
    float ent = 0.0f;
#pragma unroll
    for (int i = 0; i < 4; ++i) {
        float p = (float)hist[wave][lane + 64 * i] * (1.0f / 196.0f) + 1e-10f;
        ent -= p * log2f(p);
    }

    // ---- 144 windows: DCT + directional std variance ----
    float psi_sum = 0.0f;
    for (int w = lane; w < 144; w += 64) {
        int wi = w / 12;
        int wj = w - wi * 12;

        float g[3][3];
#pragma unroll
        for (int di = 0; di < 3; ++di)
#pragma unroll
            for (int dj = 0; dj < 3; ++dj)
                g[di][dj] = patch[wave][wi + di][wj + dj];

        // dct[i][l] = sum_{j,k} D[i][j] g[j][k] D[l][k]
        float t[3][3], d[3][3];
#pragma unroll
        for (int i = 0; i < 3; ++i)
#pragma unroll
            for (int k = 0; k < 3; ++k)
                t[i][k] = D[i][0] * g[0][k] + D[i][1] * g[1][k] + D[i][2] * g[2][k];
#pragma unroll
        for (int i = 0; i < 3; ++i)
#pragma unroll
            for (int l = 0; l < 3; ++l)
                d[i][l] = t[i][0] * D[l][0] + t[i][1] * D[l][1] + t[i][2] * D[l][2];

        auto std3 = [](float a, float bb, float c) {
            float m  = (a + bb + c) * (1.0f / 3.0f);
            float da = a - m, db = bb - m, dc = c - m;
            return sqrtf((da * da + db * db + dc * dc) * (1.0f / 3.0f));
        };

        float S1 = (std3(d[0][0], d[0][1], d[0][2]) +
                    std3(d[1][0], d[1][1], d[1][2]) +
                    std3(d[2][0], d[2][1], d[2][2])) * (1.0f / 3.0f);
        float S2 = (std3(d[0][0], d[1][0], d[2][0]) +
                    std3(d[0][1], d[1][1], d[2][1]) +
                    std3(d[0][2], d[1][2], d[2][2])) * (1.0f / 3.0f);
        float S3 = std3(d[0][0], d[1][1], d[2][2]);
        float S4 = std3(d[0][2], d[1][1], d[2][0]);   // diag of flip(last axis)

        float S   = (S1 + S2 + S3 + S4) * 0.25f + 1e-8f;
        float inv = 1.0f / S;
        float r1 = S1 * inv, r2 = S2 * inv, r3 = S3 * inv, r4 = S4 * inv;
        float mr = (r1 + r2 + r3 + r4) * 0.25f;
        float e1 = r1 - mr, e2 = r2 - mr, e3 = r3 - mr, e4 = r4 - mr;
        psi_sum += (e1 * e1 + e2 * e2 + e3 * e3 + e4 * e4) * (1.0f / 3.0f); // ddof=1
    }

    // ---- wave reduction (64 lanes) of ent and psi_sum ----
#pragma unroll
    for (int off = 32; off > 0; off >>= 1) {
        ent     += __shfl_xor(ent, off, 64);
        psi_sum += __shfl_xor(psi_sum, off, 64);
    }

    if (lane == 0) partial[wave] = (psi_sum * (1.0f / 144.0f)) * ent;
    __syncthreads();

    if (threadIdx.x == 0)
        out[bid] = (partial[0] + partial[1] + partial[2]) * (1.0f / 3.0f);
}

extern "C" void kernel_launch(void* const* d_in, const int* in_sizes, int n_in,
                              void* d_out, int out_size, void* d_ws, size_t ws_size,
                              hipStream_t stream) {
    const float* x    = (const float*)d_in[0];
    const float* dctm = (const float*)d_in[1];
    float* out        = (float*)d_out;

    // grid = B*Hp*Wp = 16*32*32 = 16384 blocks; 192 threads = 3 waves (one per channel)
    richness_kernel<<<16384, 192, 0, stream>>>(x, dctm, out);
}

// Round 2
// 54.814 us; speedup vs baseline: 1.7540x; 1.7540x over previous
//
#include <hip/hip_runtime.h>
#include <math.h>

// x: (16,3,448,448) fp32; 14x14 patches -> Hp=Wp=32; 3x3 DCT over 12x12 windows
// out: (16,32,32) fp32

__device__ __forceinline__ float fsqrt_fast(float x) { return __builtin_amdgcn_sqrtf(x); } // v_sqrt_f32
__device__ __forceinline__ float frcp_fast(float x)  { return __builtin_amdgcn_rcpf(x);  } // v_rcp_f32
__device__ __forceinline__ float flog2_fast(float x) { return __builtin_amdgcn_logf(x);  } // v_log_f32 = log2

__device__ __forceinline__ float std3_fast(float a, float b, float c) {
    // std (ddof=0) of 3 values via E[x^2]-E[x]^2; clamp tiny negative from rounding
    float s = a + b + c;
    float q = fmaf(a, a, fmaf(b, b, c * c));
    float v = fmaf(q, (1.0f / 3.0f), (s * s) * (-1.0f / 9.0f));
    return fsqrt_fast(fmaxf(v, 0.0f));
}

__global__ __launch_bounds__(192) void richness_kernel(
    const float* __restrict__ x,
    const float* __restrict__ dctm,
    float* __restrict__ out)
{
    const int bid  = blockIdx.x;          // b*1024 + hp*32 + wp
    const int wp   = bid & 31;
    const int hp   = (bid >> 5) & 31;
    const int b    = bid >> 10;
    const int wave = threadIdx.x >> 6;    // channel 0..2
    const int lane = threadIdx.x & 63;

    __shared__ float patch[3][14][17];    // stride 17 to spread banks
    __shared__ int   hist[3][256];
    __shared__ float partial[3];

    // 3x3 DCT structure: D row0 = ca*(1,1,1); row1 = cb*(1, ~0, -1); row2 = cc*(1,-2,1)
    // (D[1][1] = sqrt(2/3)*cos(pi/2) ~ 6e-17 -> contributes ~1e-16, ignored)
    const float ca = dctm[0];
    const float cb = dctm[3];
    const float cc = dctm[6];

    for (int i = lane; i < 256; i += 64) hist[wave][i] = 0;
    __syncthreads();

    // ---- stage patch (float2 vectorized) + histogram ----
    const float* src = x + (((size_t)(b * 3 + wave) * 448 + hp * 14) * 448) + wp * 14;
    for (int idx = lane; idx < 98; idx += 64) {       // 14 rows x 7 float2
        int r = idx / 7;
        int q = (idx - r * 7) * 2;
        float2 v = *reinterpret_cast<const float2*>(src + r * 448 + q);
        patch[wave][r][q]     = v.x;
        patch[wave][r][q + 1] = v.y;
        int b0 = (int)rintf(v.x * 255.0f); b0 = min(max(b0, 0), 255);
        int b1 = (int)rintf(v.y * 255.0f); b1 = min(max(b1, 0), 255);
        atomicAdd(&hist[wave][b0], 1);
        atomicAdd(&hist[wave][b1], 1);
    }
    __syncthreads();

    // ---- entropy: 4 bins/lane; ent = -sum p*log2(p) ----
    float negent = 0.0f;
#pragma unroll
    for (int i = 0; i < 4; ++i) {
        float p = (float)hist[wave][lane + 64 * i] * (1.0f / 196.0f) + 1e-10f;
        negent = fmaf(p, flog2_fast(p), negent);
    }

    // ---- 144 sliding windows: structured 3x3 DCT + directional-std variance ----
    float psi_sum = 0.0f;
    for (int w = lane; w < 144; w += 64) {
        const int wi = w / 12;
        const int wj = w - wi * 12;

        float g00 = patch[wave][wi    ][wj    ], g01 = patch[wave][wi    ][wj + 1], g02 = patch[wave][wi    ][wj + 2];
        float g10 = patch[wave][wi + 1][wj    ], g11 = patch[wave][wi + 1][wj + 1], g12 = patch[wave][wi + 1][wj + 2];
        float g20 = patch[wave][wi + 2][wj    ], g21 = patch[wave][wi + 2][wj + 1], g22 = patch[wave][wi + 2][wj + 2];

        // vertical DCT (per column k): t0=ca*(g0+g1+g2), t1=cb*(g0-g2), t2=cc*(g0-2g1+g2)
        float s0 = g00 + g20, s1 = g01 + g21, s2 = g02 + g22;
        float t00 = ca * (s0 + g10), t01 = ca * (s1 + g11), t02 = ca * (s2 + g12);
        float t10 = cb * (g00 - g20), t11 = cb * (g01 - g21), t12 = cb * (g02 - g22);
        float t20 = cc * fmaf(-2.0f, g10, s0), t21 = cc * fmaf(-2.0f, g11, s1), t22 = cc * fmaf(-2.0f, g12, s2);

        // horizontal DCT (per row i): d_i0=ca*(ti0+ti1+ti2), d_i1=cb*(ti0-ti2), d_i2=cc*(ti0-2ti1+ti2)
        float r0, d00, d01, d02, d10, d11, d12, d20, d21, d22;
        r0 = t00 + t02; d00 = ca * (r0 + t01); d01 = cb * (t00 - t02); d02 = cc * fmaf(-2.0f, t01, r0);
        r0 = t10 + t12; d10 = ca * (r0 + t11); d11 = cb * (t10 - t12); d12 = cc * fmaf(-2.0f, t11, r0);
        r0 = t20 + t22; d20 = ca * (r0 + t21); d21 = cb * (t20 - t22); d22 = cc * fmaf(-2.0f, t21, r0);

        // directional stds
        float S1 = (std3_fast(d00, d01, d02) + std3_fast(d10, d11, d12) + std3_fast(d20, d21, d22)) * (1.0f / 3.0f);
        float S2 = (std3_fast(d00, d10, d20) + std3_fast(d01, d11, d21) + std3_fast(d02, d12, d22)) * (1.0f / 3.0f);
        float S3 = std3_fast(d00, d11, d22);
        float S4 = std3_fast(d02, d11, d20);

        // psi = Var_ddof1(S_i/S) = (sumQ - sumS^2/4) / (3*S^2),  S = sumS/4 + 1e-8
        float sumS = (S1 + S2) + (S3 + S4);
        float sumQ = fmaf(S1, S1, fmaf(S2, S2, fmaf(S3, S3, S4 * S4)));
        float h    = fmaxf(fmaf(-0.25f * sumS, sumS, sumQ), 0.0f);
        float S    = fmaf(sumS, 0.25f, 1e-8f);
        float inv  = frcp_fast(S);
        psi_sum    = fmaf(h * inv * inv, (1.0f / 3.0f), psi_sum);
    }

    // ---- wave reduction over 64 lanes ----
#pragma unroll
    for (int off = 32; off > 0; off >>= 1) {
        negent  += __shfl_xor(negent, off, 64);
        psi_sum += __shfl_xor(psi_sum, off, 64);
    }

    if (lane == 0) partial[wave] = (psi_sum * (1.0f / 144.0f)) * (-negent);
    __syncthreads();

    if (threadIdx.x == 0)
        out[bid] = (partial[0] + partial[1] + partial[2]) * (1.0f / 3.0f);
}

extern "C" void kernel_launch(void* const* d_in, const int* in_sizes, int n_in,
                              void* d_out, int out_size, void* d_ws, size_t ws_size,
                              hipStream_t stream) {
    const float* x    = (const float*)d_in[0];
    const float* dctm = (const float*)d_in[1];
    float* out        = (float*)d_out;

    richness_kernel<<<16384, 192, 0, stream>>>(x, dctm, out);
}

// Round 3
// 49.795 us; speedup vs baseline: 1.9308x; 1.1008x over previous
//
#include <hip/hip_runtime.h>
#include <math.h>

// x: (16,3,448,448) fp32; 14x14 patches -> Hp=Wp=32; 3x3 DCT over 12x12 sliding windows
// out: (16,32,32) fp32
//
// Block = 8 consecutive patches (same b,hp; wp0..wp0+7) x 3 channels = 24 patch-channels.
// 192 threads. Each thread: 3 sliding runs of 6 windows (3456 windows/block, exactly 18/thread).
// grid = 16 * 32 * 4 = 2048 blocks.

typedef unsigned int uint32;

__device__ __forceinline__ float fsqrt_fast(float x) { return __builtin_amdgcn_sqrtf(x); } // v_sqrt_f32
__device__ __forceinline__ float frcp_fast(float x)  { return __builtin_amdgcn_rcpf(x);  } // v_rcp_f32
__device__ __forceinline__ float flog2_fast(float x) { return __builtin_amdgcn_logf(x);  } // v_log_f32

__device__ __forceinline__ float std3_fast(float a, float b, float c) {
    // ddof=0 std of 3 via E[x^2]-E[x]^2 (clamped)
    float s = a + b + c;
    float q = fmaf(a, a, fmaf(b, b, c * c));
    float v = fmaf(q, (1.0f / 3.0f), (s * s) * (-1.0f / 9.0f));
    return fsqrt_fast(fmaxf(v, 0.0f));
}

__global__ __launch_bounds__(192) void richness_kernel(
    const float* __restrict__ x,
    const float* __restrict__ dctm,
    float* __restrict__ out)
{
    const int bid = blockIdx.x;       // b*128 + hp*4 + wpg
    const int wpg = bid & 3;          // group of 8 patches along wp
    const int hp  = (bid >> 2) & 31;
    const int b   = bid >> 7;
    const int tid = threadIdx.x;

    // LDS: patch stride 116 (20 mod 32 -> worst 2-way bank alias; 464B is 16B-aligned)
    __shared__ __align__(16) float patch[3][14][116];
    __shared__ uint32 hist32[12][256];   // pc pair-packed u16 counts (counts <= 196)
    __shared__ float  psiPart[24][24];   // [pc][run-within-pc]
    __shared__ float  entAcc[24];
    __shared__ float  richAcc[24];

    // DCT structure: row0 = k0*(1,1,1); row1 = k1*(1,0,-1) (D[1][1]~6e-17); row2 = k2*(1,-2,1)
    const float k0 = dctm[0];
    const float k1 = dctm[3];
    const float k2 = dctm[6];

    // ---- init ----
    for (int i = tid; i < 12 * 256; i += 192) ((uint32*)hist32)[i] = 0u;
    __syncthreads();

    // ---- stage 3ch x 14 x 112 region (float4) + histogram ----
    for (int t = tid; t < 1176; t += 192) {          // 3 * 14 * 28 float4 tasks
        int ch  = t / 392;                           // 392 = 14*28
        int rem = t - ch * 392;
        int row = rem / 28;
        int col = (rem - row * 28) * 4;
        const float* src = x + (((size_t)(b * 3 + ch) * 448 + hp * 14 + row) * 448) + wpg * 112 + col;
        float4 v = *reinterpret_cast<const float4*>(src);
        *reinterpret_cast<float4*>(&patch[ch][row][col]) = v;
#pragma unroll
        for (int e = 0; e < 4; ++e) {
            float val = (&v.x)[e];
            int bin = (int)rintf(val * 255.0f);      // round-half-even == np.round
            bin = min(max(bin, 0), 255);
            int ce = col + e;
            int p  = (ce * 2341) >> 15;              // ce/14 for ce<112
            int pc = ch * 8 + p;
            atomicAdd(&hist32[pc >> 1][bin], 1u << ((pc & 1) * 16));
        }
    }
    __syncthreads();

    // ---- entropy: 8 threads per pc, 32 bins each ----
    {
        const int pcE = tid >> 3, sub = tid & 7;
        const int rowW = pcE >> 1, sh = (pcE & 1) * 16;
        float negent = 0.0f;
#pragma unroll
        for (int kk = 0; kk < 32; ++kk) {
            uint32 c = (hist32[rowW][sub + 8 * kk] >> sh) & 0xffffu;
            float pr = (float)c * (1.0f / 196.0f) + 1e-10f;
            negent = fmaf(pr, flog2_fast(pr), negent);
        }
#pragma unroll
        for (int off = 1; off < 8; off <<= 1) negent += __shfl_xor(negent, off, 64);
        if (sub == 0) entAcc[pcE] = -negent;
    }

    // ---- sliding windows: 3 runs of 6 windows per thread ----
#define LOADT(J, T0, T1, T2) {                                        \
        float v0 = prow[(J)], v1 = prow[116 + (J)], v2 = prow[232 + (J)]; \
        float s_ = v0 + v2;                                           \
        T0 = k0 * (s_ + v1);                                          \
        T1 = k1 * (v0 - v2);                                          \
        T2 = k2 * fmaf(-2.0f, v1, s_); }

#define WIN(X0, X1, X2, Y0, Y1, Y2, Z0, Z1, Z2) {                             \
        float xz0 = X0 + Z0, xz1 = X1 + Z1, xz2 = X2 + Z2;                    \
        float d00 = k0 * (xz0 + Y0), d01 = k1 * (X0 - Z0), d02 = k2 * fmaf(-2.0f, Y0, xz0); \
        float d10 = k0 * (xz1 + Y1), d11 = k1 * (X1 - Z1), d12 = k2 * fmaf(-2.0f, Y1, xz1); \
        float d20 = k0 * (xz2 + Y2), d21 = k1 * (X2 - Z2), d22 = k2 * fmaf(-2.0f, Y2, xz2); \
        float S1 = (std3_fast(d00, d01, d02) + std3_fast(d10, d11, d12) + std3_fast(d20, d21, d22)) * (1.0f / 3.0f); \
        float S2 = (std3_fast(d00, d10, d20) + std3_fast(d01, d11, d21) + std3_fast(d02, d12, d22)) * (1.0f / 3.0f); \
        float S3 = std3_fast(d00, d11, d22);                                  \
        float S4 = std3_fast(d02, d11, d20);                                  \
        float sumS = (S1 + S2) + (S3 + S4);                                   \
        float sumQ = fmaf(S1, S1, fmaf(S2, S2, fmaf(S3, S3, S4 * S4)));       \
        float h    = fmaxf(fmaf(-0.25f * sumS, sumS, sumQ), 0.0f);            \
        float Sm   = fmaf(sumS, 0.25f, 1e-8f);                                \
        float inv  = frcp_fast(Sm);                                           \
        psi_run    = fmaf(h * inv * inv, (1.0f / 3.0f), psi_run); }

#pragma unroll
    for (int kr = 0; kr < 3; ++kr) {
        int rho = tid + 192 * kr;            // 0..575
        int pc  = rho / 24;                  // 0..23  (ch = pc>>3, p = pc&7)
        int rr  = rho - pc * 24;             // 0..23  (wi = rr>>1, half = rr&1)
        int wi  = rr >> 1;
        int cb  = (pc & 7) * 14 + (rr & 1) * 6;
        const float* prow = &patch[pc >> 3][wi][cb];

        float a0, a1, a2, b0, b1, b2, c0, c1, c2;
        float psi_run = 0.0f;
        LOADT(0, a0, a1, a2);
        LOADT(1, b0, b1, b2);
        LOADT(2, c0, c1, c2);  WIN(a0, a1, a2, b0, b1, b2, c0, c1, c2);
        LOADT(3, a0, a1, a2);  WIN(b0, b1, b2, c0, c1, c2, a0, a1, a2);
        LOADT(4, b0, b1, b2);  WIN(c0, c1, c2, a0, a1, a2, b0, b1, b2);
        LOADT(5, c0, c1, c2);  WIN(a0, a1, a2, b0, b1, b2, c0, c1, c2);
        LOADT(6, a0, a1, a2);  WIN(b0, b1, b2, c0, c1, c2, a0, a1, a2);
        LOADT(7, b0, b1, b2);  WIN(c0, c1, c2, a0, a1, a2, b0, b1, b2);

        psiPart[pc][rr] = psi_run;           // deterministic scoreboard
    }
#undef LOADT
#undef WIN
    __syncthreads();

    // ---- per-pc psi sum + richness ----
    if (tid < 24) {
        float s = 0.0f;
#pragma unroll
        for (int r = 0; r < 24; ++r) s += psiPart[tid][r];
        richAcc[tid] = (s * (1.0f / 144.0f)) * entAcc[tid];
    }
    __syncthreads();

    // ---- channel mean -> out ----
    if (tid < 8) {
        float r = (richAcc[tid] + richAcc[8 + tid] + richAcc[16 + tid]) * (1.0f / 3.0f);
        out[(b * 32 + hp) * 32 + wpg * 8 + tid] = r;
    }
}

extern "C" void kernel_launch(void* const* d_in, const int* in_sizes, int n_in,
                              void* d_out, int out_size, void* d_ws, size_t ws_size,
                              hipStream_t stream) {
    const float* x    = (const float*)d_in[0];
    const float* dctm = (const float*)d_in[1];
    float* out        = (float*)d_out;

    richness_kernel<<<2048, 192, 0, stream>>>(x, dctm, out);
}

// Round 4
// 38.596 us; speedup vs baseline: 2.4910x; 1.2901x over previous
//
#include <hip/hip_runtime.h>
#include <math.h>

// x: (16,3,448,448) fp32; 14x14 patches -> Hp=Wp=32; 3x3 DCT over 12x12 sliding windows
// out: (16,32,32) fp32
//
// Block = 8 consecutive patches x 3 channels = 24 patch-channels, 192 threads.
// No patch LDS: window pass reads directly from global (L1-resident, ~19 KB/block,
// warmed by the coalesced histogram pass). LDS only for histograms (u8 x4-packed),
// psi scoreboard, and tiny accumulators (~8.7 KB) -> occupancy limited only by
// VGPR; __launch_bounds__(192,8) forces <=64 VGPR for the 8-waves/SIMD bucket.

typedef unsigned int uint32;

__device__ __forceinline__ float fsqrt_fast(float x) { return __builtin_amdgcn_sqrtf(x); } // v_sqrt_f32
__device__ __forceinline__ float frcp_fast(float x)  { return __builtin_amdgcn_rcpf(x);  } // v_rcp_f32
__device__ __forceinline__ float flog2_fast(float x) { return __builtin_amdgcn_logf(x);  } // v_log_f32

__device__ __forceinline__ float std3_fast(float a, float b, float c) {
    // ddof=0 std of 3 via E[x^2]-E[x]^2 (clamped)
    float s = a + b + c;
    float q = fmaf(a, a, fmaf(b, b, c * c));
    float v = fmaf(q, (1.0f / 3.0f), (s * s) * (-1.0f / 9.0f));
    return fsqrt_fast(fmaxf(v, 0.0f));
}

__global__ __launch_bounds__(192, 8) void richness_kernel(
    const float* __restrict__ x,
    const float* __restrict__ dctm,
    float* __restrict__ out)
{
    const int bid = blockIdx.x;       // b*128 + hp*4 + wpg
    const int wpg = bid & 3;          // group of 8 patches along wp
    const int hp  = (bid >> 2) & 31;
    const int b   = bid >> 7;
    const int tid = threadIdx.x;

    __shared__ uint32 hist[6][256];      // 4 pcs per word, u8 counts (max 196, no carry)
    __shared__ float  psiPart[24][24];   // [pc][run]
    __shared__ float  entAcc[24];
    __shared__ float  richAcc[24];

    // DCT structure: row0 = k0*(1,1,1); row1 = k1*(1,0,-1) (D[1][1]~6e-17); row2 = k2*(1,-2,1)
    const float k0 = dctm[0];
    const float k1 = dctm[3];
    const float k2 = dctm[6];

    for (int i = tid; i < 6 * 256; i += 192) ((uint32*)hist)[i] = 0u;
    __syncthreads();

    // ---- coalesced histogram pass (also warms L1/L2 for the window pass) ----
    for (int t = tid; t < 1176; t += 192) {          // 3ch * 14 rows * 28 float4
        int ch  = t / 392;                           // 392 = 14*28
        int rem = t - ch * 392;
        int row = rem / 28;
        int col = (rem - row * 28) * 4;
        const float* src = x + (((size_t)(b * 3 + ch) * 448 + hp * 14 + row) * 448) + wpg * 112 + col;
        float4 v = *reinterpret_cast<const float4*>(src);
#pragma unroll
        for (int e = 0; e < 4; ++e) {
            float val = (&v.x)[e];
            int bin = (int)rintf(val * 255.0f);      // round-half-even == np.round
            bin = min(max(bin, 0), 255);
            int ce = col + e;
            int p  = (ce * 2341) >> 15;              // ce/14 for ce<112
            int pc = ch * 8 + p;
            atomicAdd(&hist[pc >> 2][bin], 1u << ((pc & 3) * 8));
        }
    }
    // NOTE: no sync needed here — window pass is independent of hist;
    // the atomics drain underneath the window compute.

    // ---- sliding windows: 3 runs of 6 windows per thread, inputs direct from global ----
#pragma unroll
    for (int kr = 0; kr < 3; ++kr) {
        int rho  = tid + 192 * kr;           // 0..575
        int pc   = rho / 24;                 // 0..23
        int rr   = rho - pc * 24;            // 0..23
        int ch   = pc >> 3, p = pc & 7;
        int wi   = rr >> 1, half = rr & 1;
        const float* base = x + (((size_t)(b * 3 + ch) * 448 + hp * 14 + wi) * 448)
                              + wpg * 112 + p * 14 + half * 6;

        // 3 rows x 8 cols; row offsets 1792/3584 B and col offsets fold to load immediates
        float r0[8], r1[8], r2[8];
#pragma unroll
        for (int c2 = 0; c2 < 4; ++c2) {
            float2 a = *reinterpret_cast<const float2*>(base + c2 * 2);
            float2 bbv = *reinterpret_cast<const float2*>(base + 448 + c2 * 2);
            float2 cv = *reinterpret_cast<const float2*>(base + 896 + c2 * 2);
            r0[c2 * 2] = a.x;  r0[c2 * 2 + 1] = a.y;
            r1[c2 * 2] = bbv.x; r1[c2 * 2 + 1] = bbv.y;
            r2[c2 * 2] = cv.x; r2[c2 * 2 + 1] = cv.y;
        }

        // vertical DCT triples for all 8 columns
        float t0[8], t1[8], t2[8];
#pragma unroll
        for (int J = 0; J < 8; ++J) {
            float s = r0[J] + r2[J];
            t0[J] = k0 * (s + r1[J]);
            t1[J] = k1 * (r0[J] - r2[J]);
            t2[J] = k2 * fmaf(-2.0f, r1[J], s);
        }

        float psi_run = 0.0f;
#pragma unroll
        for (int j = 0; j < 6; ++j) {
            float X0 = t0[j],     X1 = t1[j],     X2 = t2[j];
            float Y0 = t0[j + 1], Y1 = t1[j + 1], Y2 = t2[j + 1];
            float Z0 = t0[j + 2], Z1 = t1[j + 2], Z2 = t2[j + 2];
            float xz0 = X0 + Z0, xz1 = X1 + Z1, xz2 = X2 + Z2;
            float d00 = k0 * (xz0 + Y0), d01 = k1 * (X0 - Z0), d02 = k2 * fmaf(-2.0f, Y0, xz0);
            float d10 = k0 * (xz1 + Y1), d11 = k1 * (X1 - Z1), d12 = k2 * fmaf(-2.0f, Y1, xz1);
            float d20 = k0 * (xz2 + Y2), d21 = k1 * (X2 - Z2), d22 = k2 * fmaf(-2.0f, Y2, xz2);

            float S1 = (std3_fast(d00, d01, d02) + std3_fast(d10, d11, d12) + std3_fast(d20, d21, d22)) * (1.0f / 3.0f);
            float S2 = (std3_fast(d00, d10, d20) + std3_fast(d01, d11, d21) + std3_fast(d02, d12, d22)) * (1.0f / 3.0f);
            float S3 = std3_fast(d00, d11, d22);
            float S4 = std3_fast(d02, d11, d20);

            float sumS = (S1 + S2) + (S3 + S4);
            float sumQ = fmaf(S1, S1, fmaf(S2, S2, fmaf(S3, S3, S4 * S4)));
            float h    = fmaxf(fmaf(-0.25f * sumS, sumS, sumQ), 0.0f);
            float Sm   = fmaf(sumS, 0.25f, 1e-8f);
            float inv  = frcp_fast(Sm);
            psi_run    = fmaf(h * inv * inv, (1.0f / 3.0f), psi_run);
        }
        psiPart[pc][rr] = psi_run;
    }
    __syncthreads();   // hist atomics + psiPart complete

    // ---- entropy: 8 threads per pc, 32 bins each ----
    {
        const int pcE = tid >> 3, sub = tid & 7;
        const int rowW = pcE >> 2, sh = (pcE & 3) * 8;
        float negent = 0.0f;
#pragma unroll
        for (int kk = 0; kk < 32; ++kk) {
            uint32 c = (hist[rowW][sub + 8 * kk] >> sh) & 0xffu;
            float pr = (float)c * (1.0f / 196.0f) + 1e-10f;
            negent = fmaf(pr, flog2_fast(pr), negent);
        }
#pragma unroll
        for (int off = 1; off < 8; off <<= 1) negent += __shfl_xor(negent, off, 64);
        if (sub == 0) entAcc[pcE] = -negent;
    }
    __syncthreads();

    // ---- per-pc psi sum + richness ----
    if (tid < 24) {
        float s = 0.0f;
#pragma unroll
        for (int r = 0; r < 24; ++r) s += psiPart[tid][r];
        richAcc[tid] = (s * (1.0f / 144.0f)) * entAcc[tid];
    }
    __syncthreads();

    // ---- channel mean -> out ----
    if (tid < 8) {
        float r = (richAcc[tid] + richAcc[8 + tid] + richAcc[16 + tid]) * (1.0f / 3.0f);
        out[(b * 32 + hp) * 32 + wpg * 8 + tid] = r;
    }
}

extern "C" void kernel_launch(void* const* d_in, const int* in_sizes, int n_in,
                              void* d_out, int out_size, void* d_ws, size_t ws_size,
                              hipStream_t stream) {
    const float* x    = (const float*)d_in[0];
    const float* dctm = (const float*)d_in[1];
    float* out        = (float*)d_out;

    richness_kernel<<<2048, 192, 0, stream>>>(x, dctm, out);
}